// Round 18
// baseline (114.859 us; speedup 1.0000x reference)
//
#include <hip/hip_runtime.h>

// SemanticCaps dynamic routing, fp32. B=128, J=10, K=1152, M=16, I=8.
// R23 = R22 (109.9 µs, MFMA precision-triple) + CO-RESIDENCY: grid (128,4),
// 32 batches/block -> LDS 57 KB -> 2 blocks/CU (was 1). R21/R22 pattern:
// VALUBusy ~50%, occ 28%, pipe floor ~2.5-3 µs/pass vs ~8-10 measured ->
// latency/convoy-bound at 1 block/CU; a sibling block fills barrier and
// LDS/MFMA latency bubbles. Ws staging duplicated x4 (FETCH ~26 MB/pass,
// +~3 µs HBM — accepted). MFMA core unchanged: one 16x16x32 bf16 MFMA per
// (j,k,subtile), K-slots = [Whi|Wlo|Whi|0]x[xhi|xhi|xlo|-] (Wlo·xlo
// dropped, ~2^-18); den deduped via wave 0 + 2nd barrier.
// Falsified: LDS/scalar/vector Ws shuffles (R6/R18/R19), pipelining (R11),
// barrier count (R16), grid-sync (R3/R10), atomics (R4/R8), thin threads
// (R14), occupancy caps (R12).
// b-logit algebra: b after t iters = u.(v0+..+v_{t-1}) (b starts at 0).
//
// ws (floats): sp[128*10*128*16] v0T[20480] vsumT[20480]

#define B_ 128
#define J_ 10
#define K_ 1152
#define M_ 16
#define I_ 8
#define KT 9
#define NKT (K_ / KT)        // 128 k-tiles
#define BB 32                // batches per block (was 64)
#define NS (BB / 16)         // 2 MFMA subtiles per wave per k
#define RW (K_ * I_)         // 9216 floats per x batch-row
#define SVEC (J_ * B_ * M_)  // 20480 floats per fold-slice of sp
#define XT4 (KT * I_ / 4)    // 18 float4 per b-row of the x tile
#define WTOT (J_ * KT * M_ * I_)   // 11520 Ws elements per block
#define XTOT (KT * BB * I_)        // 2304 x elements per block

typedef short bf16x8 __attribute__((ext_vector_type(8)));
typedef float f32x4  __attribute__((ext_vector_type(4)));

__device__ __forceinline__ ushort bf_hi(float f) {
    return (ushort)(__float_as_uint(f) >> 16);   // truncate; residual in lo
}
__device__ __forceinline__ float bf_f(ushort h) {
    return __uint_as_float((unsigned)h << 16);
}

// ---------- routing pass -----------------------------------------------------
// MODE 0: c == 1 (iteration 0; 0.1 folded into squash<0>); acc chains in MFMA C.
// MODE 1: c = softmax_j(u . vin); per-k D=A·B, softmax, acc += c*D.
// Wave = output capsule j (10 waves); lane: col=l&15, g=l>>4 (K-slot group /
// m-row group). NS=2 subtiles cover the block's 32 b.
template <int MODE>
__global__ __launch_bounds__(640)
void iter_kernel(const float* __restrict__ x, const float* __restrict__ Ws,
                 const float* __restrict__ vinT, float* __restrict__ sp) {
    __shared__ __align__(16) ushort whi[WTOT];   // [(j*KT+kk)*128 + m*8 + i]
    __shared__ __align__(16) ushort wlo[WTOT];
    __shared__ __align__(16) ushort xhi[XTOT];   // [(kk*BB + b)*8 + i]
    __shared__ __align__(16) ushort xlo[XTOT];
    __shared__ __align__(16) ushort zpad[8];     // 16B zeros (A group-3 slots)
    __shared__ float earr[J_ * BB];
    __shared__ float denl[BB];

    const int t   = threadIdx.x;
    const int l   = t & 63;
    const int j   = __builtin_amdgcn_readfirstlane(t >> 6);  // wave-uniform j
    const int kt  = blockIdx.x, bg = blockIdx.y;             // bg in 0..3
    const int col = l & 15;
    const int g   = l >> 4;

    // ---- stage Ws tile -> bf16 hi/lo ---------------------------------------
    {
        const float4* ws4 = (const float4*)Ws;
        for (int idx = t; idx < WTOT / 4; idx += 640) {          // 2880 float4
            const int jj = idx / (KT * 32);
            const int r  = idx % (KT * 32);
            const int kk = r / 32, q = r % 32;
            const float4 w = ws4[((size_t)jj * K_ + (size_t)kt * KT + kk) * 32 + q];
            const int base = (jj * KT + kk) * 128 + q * 4;
            ushort4 hv, lv;
            hv.x = bf_hi(w.x); lv.x = bf_hi(w.x - bf_f(hv.x));
            hv.y = bf_hi(w.y); lv.y = bf_hi(w.y - bf_f(hv.y));
            hv.z = bf_hi(w.z); lv.z = bf_hi(w.z - bf_f(hv.z));
            hv.w = bf_hi(w.w); lv.w = bf_hi(w.w - bf_f(hv.w));
            *(ushort4*)(whi + base) = hv;
            *(ushort4*)(wlo + base) = lv;
        }
    }
    // ---- stage x tile -> bf16 hi/lo ----------------------------------------
    {
        const float4* x4 = (const float4*)x;     // row stride RW/4 = 2304
        for (int idx = t; idx < BB * XT4; idx += 640) {          // 576 float4
            const int bb = idx / XT4, q = idx % XT4;
            const float4 w = x4[(size_t)(bg * BB + bb) * (RW / 4) + kt * XT4 + q];
            const int kk = q >> 1, i0 = (q & 1) * 4;
            const int base = (kk * BB + bb) * 8 + i0;
            ushort4 hv, lv;
            hv.x = bf_hi(w.x); lv.x = bf_hi(w.x - bf_f(hv.x));
            hv.y = bf_hi(w.y); lv.y = bf_hi(w.y - bf_f(hv.y));
            hv.z = bf_hi(w.z); lv.z = bf_hi(w.z - bf_f(hv.z));
            hv.w = bf_hi(w.w); lv.w = bf_hi(w.w - bf_f(hv.w));
            *(ushort4*)(xhi + base) = hv;
            *(ushort4*)(xlo + base) = lv;
        }
    }
    if (t < 8) zpad[t] = 0;

    // ---- v in MFMA-D layout: vd[s][r] = v[j][bg*BB+s*16+col][g*4+r] --------
    f32x4 vd[NS];
    if (MODE == 1) {
#pragma unroll
        for (int s = 0; s < NS; ++s)
            vd[s] = *(const f32x4*)(vinT
                      + ((size_t)j * B_ + bg * BB + s * 16 + col) * M_ + g * 4);
    }
    __syncthreads();   // tiles ready

    f32x4 acc[NS];
#pragma unroll
    for (int s = 0; s < NS; ++s) acc[s] = (f32x4){0.f, 0.f, 0.f, 0.f};

    // A source per lane group: g0/g2 -> Whi, g1 -> Wlo, g3 -> zeros.
    const ushort* asrc = (g == 1) ? wlo : ((g == 3) ? zpad : whi);
    const int     amul = (g == 3) ? 0 : 1;
    // B source: slots g0/g1 -> xhi, g2 -> xlo (g3 arbitrary: A=0).
    const ushort* bsrc = (g >= 2) ? xlo : xhi;

    for (int kk = 0; kk < KT; ++kk) {
        const bf16x8 af =
            *(const bf16x8*)(asrc + amul * ((j * KT + kk) * 128 + col * 8));
        f32x4 dd[NS];
#pragma unroll
        for (int s = 0; s < NS; ++s) {
            const bf16x8 bf =
                *(const bf16x8*)(bsrc + (kk * BB + s * 16 + col) * 8);
            if (MODE == 0) {
                acc[s] = __builtin_amdgcn_mfma_f32_16x16x32_bf16(af, bf, acc[s], 0, 0, 0);
            } else {
                dd[s] = __builtin_amdgcn_mfma_f32_16x16x32_bf16(
                            af, bf, (f32x4){0.f, 0.f, 0.f, 0.f}, 0, 0, 0);
            }
        }

        if (MODE == 1) {
            float es[NS];
#pragma unroll
            for (int s = 0; s < NS; ++s) {
                float p = dd[s][0] * vd[s][0] + dd[s][1] * vd[s][1]
                        + dd[s][2] * vd[s][2] + dd[s][3] * vd[s][3];
                p += __shfl_xor(p, 16, 64);
                p += __shfl_xor(p, 32, 64);   // sum the 4 m-row groups
                es[s] = __expf(p);            // logit[b = s*16+col], all lanes
            }
            if (l < BB)                       // lane l owns b = l
                earr[j * BB + l] = (l & 16) ? es[1] : es[0];
            __syncthreads();                  // barrier 1: e complete
            if (j == 0 && l < BB) {           // dedup: wave 0 computes den[b]
                float den = 0.f;
#pragma unroll
                for (int jj = 0; jj < J_; ++jj) den += earr[jj * BB + l];
                denl[l] = den;
            }
            __syncthreads();                  // barrier 2: den ready
#pragma unroll
            for (int s = 0; s < NS; ++s) {
                const float c = __fdividef(es[s], denl[s * 16 + col]);
#pragma unroll
                for (int r = 0; r < 4; ++r) acc[s][r] += c * dd[s][r];
            }
        }
    }

    // ---- write: lane holds (m = g*4+r, b = s*16+col) -> sp[kt][j][b][m] ----
    float* ob = sp + (((size_t)kt * J_ + j) * B_ + bg * BB) * M_;
#pragma unroll
    for (int s = 0; s < NS; ++s)
        *(f32x4*)(ob + (s * 16 + col) * M_ + g * 4) = acc[s];
}

// ---------- squash: parallel fold of 128 tile-partials, emit v ---------------
// SM 0: v0T = squash(0.1*S)  SM 1: vsumT = v0T + squash(S)  SM 2: out = squash(S)
template <int SM>
__global__ __launch_bounds__(256)
void squash_kernel(const float* __restrict__ sp, const float* __restrict__ v0T,
                   float* __restrict__ dst) {
    __shared__ float red[4][64];
    const int t  = threadIdx.x;
    const int l  = t & 63;
    const int wv = t >> 6;
    const int g  = blockIdx.x * 64 + l;   // g = (j*128+b)*16+m
    const int m = g & 15;
    const int b = (g >> 4) & 127;
    const int j = g >> 11;
    const float* p = sp + (size_t)((j * B_ + b) * M_ + m);
    float S = 0.f;
#pragma unroll 8
    for (int tt = wv * (NKT / 4); tt < (wv + 1) * (NKT / 4); ++tt)
        S += p[(size_t)tt * SVEC];
    red[wv][l] = S;
    __syncthreads();
    if (wv == 0) {
        S = red[0][l] + red[1][l] + red[2][l] + red[3][l];
        if (SM == 0) S *= 0.1f;
        float sq = S * S;
        sq += __shfl_xor(sq, 1, 64);
        sq += __shfl_xor(sq, 2, 64);
        sq += __shfl_xor(sq, 4, 64);
        sq += __shfl_xor(sq, 8, 64);      // sum over m within 16-lane group
        const float n = sqrtf(sq);
        float v = S * (n / (1.f + sq));
        if (SM == 1) v += v0T[g];
        if (SM == 2) dst[((size_t)b * J_ + j) * M_ + m] = v;   // standard [b][j][m]
        else         dst[g] = v;                                // vT layout
    }
}

extern "C" void kernel_launch(void* const* d_in, const int* in_sizes, int n_in,
                              void* d_out, int out_size, void* d_ws, size_t ws_size,
                              hipStream_t stream) {
    const float* x  = (const float*)d_in[0];   // [128][1152][8]
    const float* Ws = (const float*)d_in[1];   // [10][1152][16][8]
    float* out = (float*)d_out;                // [128][10][16]

    float* sp    = (float*)d_ws;                           // 2,621,440 floats
    float* v0T   = sp + (size_t)NKT * SVEC;                //    20,480
    float* vsumT = v0T + SVEC;                             //    20,480

    iter_kernel<0><<<dim3(NKT, 4), 640, 0, stream>>>(x, Ws, nullptr, sp);
    squash_kernel<0><<<320, 256, 0, stream>>>(sp, nullptr, v0T);

    iter_kernel<1><<<dim3(NKT, 4), 640, 0, stream>>>(x, Ws, v0T, sp);
    squash_kernel<1><<<320, 256, 0, stream>>>(sp, v0T, vsumT);

    iter_kernel<1><<<dim3(NKT, 4), 640, 0, stream>>>(x, Ws, vsumT, sp);
    squash_kernel<2><<<320, 256, 0, stream>>>(sp, nullptr, out);
}